// Round 12
// baseline (393.759 us; speedup 1.0000x reference)
//
#include <hip/hip_runtime.h>
#include <hip/hip_fp16.h>
#include <math.h>

// GAT 2-layer. R12: agg kernels use 16B-gather lane layout (e8=lane>>3 edge,
// c8=lane&7 col-octet == head) -> weight & gather layouts coincide, zero
// per-chunk shuffles; one e8-reduction per node. v_fma_mix fp16xfp32 accum.
// kBin re-fused with MFMA tf0 (kGB, proportional mixed grid).

#define CAPS 32
#define STRIDE 33
#define NBMAX 128

typedef _Float16 h2_t  __attribute__((ext_vector_type(2)));
typedef _Float16 h8_t  __attribute__((ext_vector_type(8)));
typedef float    f4_t  __attribute__((ext_vector_type(4)));

__device__ __forceinline__ float lrelu(float v) { return v >= 0.f ? v : 0.2f * v; }
__device__ __forceinline__ float eluf(float v)  { return v > 0.f ? v : expm1f(v); }

// ---------------- prep: swizzled fp16 B-image [ct][ks][quad][col][j] ----------
__global__ void kPrep(const float* __restrict__ W0,
                      const float* __restrict__ aS0, const float* __restrict__ aD0,
                      __half* __restrict__ W0swz)
{
    for (int g = threadIdx.x; g < 1280; g += 256) {
        int col  = g & 15;
        int quad = (g >> 4) & 3;
        int ks   = (g >> 6) & 3;
        int ct   = g >> 8;
        #pragma unroll
        for (int j = 0; j < 8; j++) {
            int k = ks * 32 + quad * 8 + j;
            float v;
            if (ct < 4) {
                v = W0[k * 64 + ct * 16 + col];
            } else {
                int h = col & 7;
                const float* att = (col < 8) ? aS0 : aD0;
                v = 0.f;
                #pragma unroll
                for (int cc = 0; cc < 8; cc++)
                    v += W0[k * 64 + h * 8 + cc] * att[h * 8 + cc];
            }
            W0swz[g * 8 + j] = __float2half(v);
        }
    }
}

// ---------------- tf0 MFMA body: 8 waves/block(512), 16 rows/wave -------------
__device__ __forceinline__ void gemm_body(
    int gb, const float* __restrict__ x, int N,
    __half* __restrict__ xw, float* __restrict__ as, float* __restrict__ ad,
    h8_t* Bl)
{
    int wave = threadIdx.x >> 6, lane = threadIdx.x & 63;
    int row0 = gb * 128 + wave * 16;
    if (row0 >= N) return;
    int quad = lane >> 4, c16 = lane & 15;
    int myrow = min(row0 + c16, N - 1);
    const float* xr = x + (size_t)myrow * 128;
    h8_t a[4];
    #pragma unroll
    for (int ks = 0; ks < 4; ks++) {
        int kb = ks * 32 + quad * 8;
        float4 v0 = *(const float4*)(xr + kb);
        float4 v1 = *(const float4*)(xr + kb + 4);
        h8_t av;
        av[0] = (_Float16)v0.x; av[1] = (_Float16)v0.y;
        av[2] = (_Float16)v0.z; av[3] = (_Float16)v0.w;
        av[4] = (_Float16)v1.x; av[5] = (_Float16)v1.y;
        av[6] = (_Float16)v1.z; av[7] = (_Float16)v1.w;
        a[ks] = av;
    }
    int rbase = row0 + quad * 4;
    #pragma unroll
    for (int ct = 0; ct < 5; ct++) {
        f4_t acc = {0.f, 0.f, 0.f, 0.f};
        #pragma unroll
        for (int ks = 0; ks < 4; ks++) {
            h8_t b = Bl[(ct * 4 + ks) * 64 + lane];
            acc = __builtin_amdgcn_mfma_f32_16x16x32_f16(a[ks], b, acc, 0, 0, 0);
        }
        if (ct < 4) {
            int col = ct * 16 + c16;
            #pragma unroll
            for (int r = 0; r < 4; r++) {
                int row = rbase + r;
                if (row < N) xw[(size_t)row * 64 + col] = __float2half(acc[r]);
            }
        } else {
            #pragma unroll
            for (int r = 0; r < 4; r++) {
                int row = rbase + r;
                if (row < N) {
                    if (c16 < 8) as[(size_t)row * 8 + c16] = acc[r];
                    else         ad[(size_t)row * 8 + (c16 - 8)] = acc[r];
                }
            }
        }
    }
}

// ---------------- fused: gemm0 || binning ----------------
__global__ __launch_bounds__(512, 4) void kGB(
    const float* __restrict__ x, const __half* __restrict__ W0swz, int N,
    __half* __restrict__ xw, float* __restrict__ as, float* __restrict__ ad,
    int gemmBlocks,
    const int* __restrict__ src, const int* __restrict__ dst, int E, int perBlock,
    unsigned* __restrict__ bucketBuf, int* __restrict__ gcur, int NB, int cap,
    int binBlocks)
{
    __shared__ __align__(16) char smem[1280 * 16];   // 20.5 KB union
    int b = blockIdx.x;
    int T = gemmBlocks + binBlocks;
    int lo = (int)((long long)b * gemmBlocks / T);
    int hi = (int)((long long)(b + 1) * gemmBlocks / T);
    if (hi > lo) {
        h8_t* Bl = (h8_t*)smem;
        const float4* s = (const float4*)W0swz;
        float4* d = (float4*)smem;
        for (int i = threadIdx.x; i < 1280; i += 512) d[i] = s[i];
        __syncthreads();
        gemm_body(lo, x, N, xw, as, ad, Bl);
    } else {
        int pb = b - hi;
        unsigned* stage = (unsigned*)smem;
        int* scnt = (int*)(smem + NBMAX * STRIDE * 4);
        int tid = threadIdx.x;
        for (int i = tid; i < NB; i += 512) scnt[i] = 0;
        __syncthreads();
        int e0 = pb * perBlock, e1 = min(E, e0 + perBlock);
        for (int base = e0; base < e1; base += 512) {
            int i = base + tid;
            if (i < e1) {
                int d2 = dst[i], s2 = src[i];
                int bk = d2 >> 10;
                unsigned rec = ((unsigned)(d2 & 1023) << 22) | (unsigned)s2;
                int pos = atomicAdd(&scnt[bk], 1);
                if (pos < CAPS) {
                    stage[bk * STRIDE + pos] = rec;
                } else {
                    int g = atomicAdd(&gcur[bk], 1);
                    bucketBuf[(size_t)bk * cap + g] = rec;
                }
            }
            __syncthreads();
            if (tid < NB) {
                int n = min(scnt[tid], CAPS);
                int g16 = n & ~15;
                if (g16) {
                    int gb2 = atomicAdd(&gcur[tid], g16);
                    unsigned* gp = &bucketBuf[(size_t)tid * cap + gb2];
                    for (int j = 0; j < g16; j++) gp[j] = stage[tid * STRIDE + j];
                    for (int j = 0; j < n - g16; j++)
                        stage[tid * STRIDE + j] = stage[tid * STRIDE + g16 + j];
                    scnt[tid] = n - g16;
                } else {
                    scnt[tid] = n;
                }
            }
            __syncthreads();
        }
        if (tid < NB) {
            int n = scnt[tid];
            if (n > 0) {
                int gb2 = atomicAdd(&gcur[tid], n);
                unsigned* gp = &bucketBuf[(size_t)tid * cap + gb2];
                for (int j = 0; j < n; j++) gp[j] = stage[tid * STRIDE + j];
            }
        }
    }
}

// ---------------- phase2: per-bucket CSR build ----------------
__global__ __launch_bounds__(256) void kP2(
    const unsigned* __restrict__ bucketBuf, const int* __restrict__ gcur,
    int NB, int cap, int N, int* __restrict__ row, int* __restrict__ adj)
{
    __shared__ int deg[1024];
    __shared__ int curl[1024];
    __shared__ int sc[256];
    int b = blockIdx.x, tid = threadIdx.x;
    int lo = b << 10;
    int hi = min(N, lo + 1024);
    int cnt = hi - lo;
    int size = min(gcur[b], cap);
    sc[tid] = (tid < b) ? gcur[tid] : 0;
    __syncthreads();
    for (int off = 128; off > 0; off >>= 1) {
        if (tid < off) sc[tid] += sc[tid + off];
        __syncthreads();
    }
    int bbase = sc[0];
    __syncthreads();
    for (int i = tid; i < 1024; i += 256) deg[i] = 0;
    __syncthreads();
    const unsigned* buf = bucketBuf + (size_t)b * cap;
    for (int e = tid; e < size; e += 256) atomicAdd(&deg[buf[e] >> 22], 1);
    __syncthreads();
    int dv[4]; int s = 0;
    #pragma unroll
    for (int j = 0; j < 4; j++) { dv[j] = deg[tid * 4 + j]; s += dv[j]; }
    sc[tid] = s; __syncthreads();
    for (int off = 1; off < 256; off <<= 1) {
        int xv = (tid >= off) ? sc[tid - off] : 0;
        __syncthreads();
        sc[tid] += xv;
        __syncthreads();
    }
    int o = (tid ? sc[tid - 1] : 0);
    #pragma unroll
    for (int j = 0; j < 4; j++) {
        int loc = tid * 4 + j;
        curl[loc] = o;
        if (loc < cnt) row[lo + loc] = bbase + o;
        o += dv[j];
    }
    if (b == NB - 1 && tid == 0) row[N] = bbase + size;
    __syncthreads();
    for (int e = tid; e < size; e += 256) {
        unsigned r = buf[e];
        int l = r >> 22;
        int p = atomicAdd(&curl[l], 1);
        adj[bbase + p] = (int)(r & 0x3FFFFF);
    }
}

// ---------------- layer0 aggregation + fused layer1 transform ----------------
// lane = (e8 = lane>>3 edge-in-chunk, c8 = lane&7 col-octet == head).
__global__ __launch_bounds__(256) void k_agg8_tf1(
    const __half* __restrict__ xw, const float* __restrict__ as, const float* __restrict__ ad,
    const int* __restrict__ row, const int* __restrict__ adj,
    const float* __restrict__ bias, const float* __restrict__ W1,
    const float* __restrict__ aS1, const float* __restrict__ aD1,
    int N, __half* __restrict__ hw, float* __restrict__ as1, float* __restrict__ ad1)
{
    __shared__ h2_t Wl2[32 * 64];
    __shared__ h2_t hst[4 * 32];
    for (int i = threadIdx.x; i < 32 * 64; i += 256) {
        int k2 = i >> 6, c = i & 63;
        h2_t v;
        v.x = (_Float16)W1[(2 * k2) * 64 + c];
        v.y = (_Float16)W1[(2 * k2 + 1) * 64 + c];
        Wl2[i] = v;
    }
    __syncthreads();
    int wv = threadIdx.x >> 6;
    int n = (blockIdx.x * 256 + threadIdx.x) >> 6;
    int lane = threadIdx.x & 63;
    if (n >= N) return;
    int rs = row[n], re = row[n + 1];
    int e8 = lane >> 3;
    int c8 = lane & 7;          // head of this lane's column octet
    float adv = ad[(size_t)n * 8 + c8];
    float shift = lrelu(as[(size_t)n * 8 + c8] + adv);
    float acc[8];
    {
        h8_t xv = *(const h8_t*)(xw + (size_t)n * 64 + c8 * 8);   // self, w=1
        #pragma unroll
        for (int i = 0; i < 8; i++) acc[i] = (e8 == 0) ? (float)xv[i] : 0.f;
    }
    float dsum = 0.f;
    int j = rs;
    bool anyC = j < re;
    int  jjC  = j + e8;
    bool vC   = jjC < re;
    int  sC   = anyC ? adj[vC ? jjC : rs] : 0;
    float eC  = anyC ? lrelu(as[(size_t)sC * 8 + c8] + adv) : 0.f;
    while (anyC) {
        int jn = j + 8;
        bool anyN = jn < re;
        int  jjN  = jn + e8;
        bool vN   = jjN < re;
        int  sN   = anyN ? adj[vN ? jjN : rs] : 0;                 // prefetch adj
        float w = vC ? __expf(eC - shift) : 0.f;
        dsum += w;
        float eN = anyN ? lrelu(as[(size_t)sN * 8 + c8] + adv) : 0.f; // prefetch logit
        h8_t xv = *(const h8_t*)(xw + (size_t)sC * 64 + c8 * 8);   // 16B gather
        #pragma unroll
        for (int i = 0; i < 8; i++) acc[i] = fmaf(w, (float)xv[i], acc[i]);
        sC = sN; eC = eN; vC = vN; j = jn; anyC = anyN;
    }
    // reduce over the 8 edge groups
    #pragma unroll
    for (int off = 8; off <= 32; off <<= 1) {
        dsum += __shfl_xor(dsum, off, 64);
        #pragma unroll
        for (int i = 0; i < 8; i++) acc[i] += __shfl_xor(acc[i], off, 64);
    }
    float denom = 1.f + dsum;   // per lane: its head's denominator
    float4 bA = *(const float4*)(bias + c8 * 8);
    float4 bB = *(const float4*)(bias + c8 * 8 + 4);
    float h[8];
    h[0] = eluf(acc[0] / denom + bA.x); h[1] = eluf(acc[1] / denom + bA.y);
    h[2] = eluf(acc[2] / denom + bA.z); h[3] = eluf(acc[3] / denom + bA.w);
    h[4] = eluf(acc[4] / denom + bB.x); h[5] = eluf(acc[5] / denom + bB.y);
    h[6] = eluf(acc[6] / denom + bB.z); h[7] = eluf(acc[7] / denom + bB.w);
    // stage h row into per-wave LDS (lanes e8==0 cover all 64 cols)
    if (e8 == 0) {
        #pragma unroll
        for (int p = 0; p < 4; p++) {
            h2_t v;
            v.x = (_Float16)h[2 * p];
            v.y = (_Float16)h[2 * p + 1];
            hst[wv * 32 + c8 * 4 + p] = v;
        }
    }
    // fused tf1: lane = output col
    float a1 = 0.f;
    #pragma unroll
    for (int k2 = 0; k2 < 32; k2++) {
        h2_t hp = hst[wv * 32 + k2];
        h2_t wp = Wl2[k2 * 64 + lane];
        a1 = __builtin_amdgcn_fdot2(hp, wp, a1, false);
    }
    hw[(size_t)n * 64 + lane] = __float2half(a1);
    float ps = a1 * aS1[lane], pd = a1 * aD1[lane];
    #pragma unroll
    for (int off = 1; off < 64; off <<= 1) {
        ps += __shfl_xor(ps, off, 64);
        pd += __shfl_xor(pd, off, 64);
    }
    if (lane == 0) { as1[n] = ps; ad1[n] = pd; }
}

// ---------------- layer1 aggregation ----------------
__global__ __launch_bounds__(256) void k_agg1(
    const __half* __restrict__ hw, const float* __restrict__ as, const float* __restrict__ ad,
    const int* __restrict__ row, const int* __restrict__ adj,
    const float* __restrict__ bias, int N, float* __restrict__ outp)
{
    int n = (blockIdx.x * 256 + threadIdx.x) >> 6;
    int lane = threadIdx.x & 63;
    if (n >= N) return;
    int rs = row[n], re = row[n + 1];
    int e8 = lane >> 3;
    int c8 = lane & 7;
    float adv = ad[n];
    float shift = lrelu(as[n] + adv);
    float acc[8];
    {
        h8_t xv = *(const h8_t*)(hw + (size_t)n * 64 + c8 * 8);
        #pragma unroll
        for (int i = 0; i < 8; i++) acc[i] = (e8 == 0) ? (float)xv[i] : 0.f;
    }
    float dsum = 0.f;
    int j = rs;
    bool anyC = j < re;
    int  jjC  = j + e8;
    bool vC   = jjC < re;
    int  sC   = anyC ? adj[vC ? jjC : rs] : 0;
    float eC  = anyC ? lrelu(as[sC] + adv) : 0.f;
    while (anyC) {
        int jn = j + 8;
        bool anyN = jn < re;
        int  jjN  = jn + e8;
        bool vN   = jjN < re;
        int  sN   = anyN ? adj[vN ? jjN : rs] : 0;
        float w = vC ? __expf(eC - shift) : 0.f;
        dsum += w;
        float eN = anyN ? lrelu(as[sN] + adv) : 0.f;
        h8_t xv = *(const h8_t*)(hw + (size_t)sC * 64 + c8 * 8);
        #pragma unroll
        for (int i = 0; i < 8; i++) acc[i] = fmaf(w, (float)xv[i], acc[i]);
        sC = sN; eC = eN; vC = vN; j = jn; anyC = anyN;
    }
    #pragma unroll
    for (int off = 8; off <= 32; off <<= 1) {
        dsum += __shfl_xor(dsum, off, 64);
        #pragma unroll
        for (int i = 0; i < 8; i++) acc[i] += __shfl_xor(acc[i], off, 64);
    }
    float denom = 1.f + dsum;
    if (e8 == 0) {
        float4 bA = *(const float4*)(bias + c8 * 8);
        float4 bB = *(const float4*)(bias + c8 * 8 + 4);
        float4 o1, o2;
        o1.x = eluf(acc[0] / denom + bA.x); o1.y = eluf(acc[1] / denom + bA.y);
        o1.z = eluf(acc[2] / denom + bA.z); o1.w = eluf(acc[3] / denom + bA.w);
        o2.x = eluf(acc[4] / denom + bB.x); o2.y = eluf(acc[5] / denom + bB.y);
        o2.z = eluf(acc[6] / denom + bB.z); o2.w = eluf(acc[7] / denom + bB.w);
        *(float4*)(outp + (size_t)n * 64 + c8 * 8)     = o1;
        *(float4*)(outp + (size_t)n * 64 + c8 * 8 + 4) = o2;
    }
}

extern "C" void kernel_launch(void* const* d_in, const int* in_sizes, int n_in,
                              void* d_out, int out_size, void* d_ws, size_t ws_size,
                              hipStream_t stream)
{
    const float* x   = (const float*)d_in[0];
    const int*   ei  = (const int*)d_in[1];
    const float* W0  = (const float*)d_in[2];
    const float* aS0 = (const float*)d_in[3];
    const float* aD0 = (const float*)d_in[4];
    const float* b0  = (const float*)d_in[5];
    const float* W1  = (const float*)d_in[6];
    const float* aS1 = (const float*)d_in[7];
    const float* aD1 = (const float*)d_in[8];
    const float* b1  = (const float*)d_in[9];

    const int N = in_sizes[0] / 128;
    const int E = in_sizes[1] / 2;
    const int* srcp = ei;
    const int* dstp = ei + E;

    const int NB  = (N + 1023) >> 10;
    const int cap = E / NB + 4096;

    char* ws = (char*)d_ws;
    size_t off = 0;
    auto alloc = [&](size_t bytes) -> size_t {
        size_t o = off;
        off = (o + bytes + 255) & ~(size_t)255;
        return o;
    };
    __half* B1 = (__half*)(ws + alloc((size_t)N * 64 * 2));     // xw (half)
    size_t b2Bytes = (size_t)N * 64 * 2;
    size_t bkBytes = (size_t)NB * cap * 4;
    char*  region  = ws + alloc(b2Bytes > bkBytes ? b2Bytes : bkBytes);
    __half*   B2        = (__half*)region;     // hw overlays bucketBuf
    unsigned* bucketBuf = (unsigned*)region;
    float* as0 = (float*)(ws + alloc((size_t)N * 8 * 4));
    float* ad0 = (float*)(ws + alloc((size_t)N * 8 * 4));
    float* as1 = (float*)(ws + alloc((size_t)N * 4));
    float* ad1 = (float*)(ws + alloc((size_t)N * 4));
    int*   row = (int*)(ws + alloc((size_t)(N + 1) * 4));
    int*   adj = (int*)(ws + alloc((size_t)E * 4));
    int*  gcur = (int*)(ws + alloc((size_t)NB * 4));
    __half* W0swz = (__half*)(ws + alloc(1280 * 8 * 2));

    const int gemmBlocks = (N + 127) / 128;
    const int binBlocks  = 1024;
    const int perBlock   = (E + binBlocks - 1) / binBlocks;

    hipMemsetAsync(gcur, 0, (size_t)NB * 4, stream);
    kPrep<<<1, 256, 0, stream>>>(W0, aS0, aD0, W0swz);
    kGB<<<gemmBlocks + binBlocks, 512, 0, stream>>>(
        x, W0swz, N, B1, as0, ad0, gemmBlocks,
        srcp, dstp, E, perBlock, bucketBuf, gcur, NB, cap, binBlocks);
    kP2<<<NB, 256, 0, stream>>>(bucketBuf, gcur, NB, cap, N, row, adj);

    const int agBlocks = (N + 3) / 4;
    k_agg8_tf1<<<agBlocks, 256, 0, stream>>>(B1, as0, ad0, row, adj, b0,
                                             W1, aS1, aD1, N, B2, as1, ad1);
    k_agg1<<<agBlocks, 256, 0, stream>>>(B2, as1, ad1, row, adj, b1, N, (float*)d_out);
}

// Round 13
// 336.890 us; speedup vs baseline: 1.1688x; 1.1688x over previous
//
#include <hip/hip_runtime.h>
#include <hip/hip_fp16.h>
#include <math.h>

// GAT 2-layer. R13: agg kernels reverted to R11 half2-pairing (per-node epilogue
// cost dominates at avg degree 17 — R12 lesson). kGB fusion kept; bin branch is
// now single-pass: CAPS=48 staging, one barrier, one cooperative flush.

#define CAPS 48
#define STRIDE 49
#define NBMAX 128

typedef _Float16 h2_t  __attribute__((ext_vector_type(2)));
typedef _Float16 h8_t  __attribute__((ext_vector_type(8)));
typedef float    f4_t  __attribute__((ext_vector_type(4)));

__device__ __forceinline__ float lrelu(float v) { return v >= 0.f ? v : 0.2f * v; }
__device__ __forceinline__ float eluf(float v)  { return v > 0.f ? v : expm1f(v); }

// ---------------- prep: swizzled fp16 B-image [ct][ks][quad][col][j] ----------
__global__ void kPrep(const float* __restrict__ W0,
                      const float* __restrict__ aS0, const float* __restrict__ aD0,
                      __half* __restrict__ W0swz)
{
    for (int g = threadIdx.x; g < 1280; g += 256) {
        int col  = g & 15;
        int quad = (g >> 4) & 3;
        int ks   = (g >> 6) & 3;
        int ct   = g >> 8;
        #pragma unroll
        for (int j = 0; j < 8; j++) {
            int k = ks * 32 + quad * 8 + j;
            float v;
            if (ct < 4) {
                v = W0[k * 64 + ct * 16 + col];
            } else {
                int h = col & 7;
                const float* att = (col < 8) ? aS0 : aD0;
                v = 0.f;
                #pragma unroll
                for (int cc = 0; cc < 8; cc++)
                    v += W0[k * 64 + h * 8 + cc] * att[h * 8 + cc];
            }
            W0swz[g * 8 + j] = __float2half(v);
        }
    }
}

// ---------------- tf0 MFMA body: 8 waves/block(512), 16 rows/wave -------------
__device__ __forceinline__ void gemm_body(
    int gb, const float* __restrict__ x, int N,
    __half* __restrict__ xw, float* __restrict__ as, float* __restrict__ ad,
    h8_t* Bl)
{
    int wave = threadIdx.x >> 6, lane = threadIdx.x & 63;
    int row0 = gb * 128 + wave * 16;
    if (row0 >= N) return;
    int quad = lane >> 4, c16 = lane & 15;
    int myrow = min(row0 + c16, N - 1);
    const float* xr = x + (size_t)myrow * 128;
    h8_t a[4];
    #pragma unroll
    for (int ks = 0; ks < 4; ks++) {
        int kb = ks * 32 + quad * 8;
        float4 v0 = *(const float4*)(xr + kb);
        float4 v1 = *(const float4*)(xr + kb + 4);
        h8_t av;
        av[0] = (_Float16)v0.x; av[1] = (_Float16)v0.y;
        av[2] = (_Float16)v0.z; av[3] = (_Float16)v0.w;
        av[4] = (_Float16)v1.x; av[5] = (_Float16)v1.y;
        av[6] = (_Float16)v1.z; av[7] = (_Float16)v1.w;
        a[ks] = av;
    }
    int rbase = row0 + quad * 4;
    #pragma unroll
    for (int ct = 0; ct < 5; ct++) {
        f4_t acc = {0.f, 0.f, 0.f, 0.f};
        #pragma unroll
        for (int ks = 0; ks < 4; ks++) {
            h8_t b = Bl[(ct * 4 + ks) * 64 + lane];
            acc = __builtin_amdgcn_mfma_f32_16x16x32_f16(a[ks], b, acc, 0, 0, 0);
        }
        if (ct < 4) {
            int col = ct * 16 + c16;
            #pragma unroll
            for (int r = 0; r < 4; r++) {
                int row = rbase + r;
                if (row < N) xw[(size_t)row * 64 + col] = __float2half(acc[r]);
            }
        } else {
            #pragma unroll
            for (int r = 0; r < 4; r++) {
                int row = rbase + r;
                if (row < N) {
                    if (c16 < 8) as[(size_t)row * 8 + c16] = acc[r];
                    else         ad[(size_t)row * 8 + (c16 - 8)] = acc[r];
                }
            }
        }
    }
}

// ---------------- fused: gemm0 || single-pass binning ----------------
__global__ __launch_bounds__(512, 4) void kGB(
    const float* __restrict__ x, const __half* __restrict__ W0swz, int N,
    __half* __restrict__ xw, float* __restrict__ as, float* __restrict__ ad,
    int gemmBlocks,
    const int* __restrict__ src, const int* __restrict__ dst, int E, int perBlock,
    unsigned* __restrict__ bucketBuf, int* __restrict__ gcur, int NB, int cap,
    int binBlocks)
{
    __shared__ __align__(16) char smem[NBMAX * STRIDE * 4 + NBMAX * 4]; // 25.6 KB union
    int b = blockIdx.x;
    int T = gemmBlocks + binBlocks;
    int lo = (int)((long long)b * gemmBlocks / T);
    int hi = (int)((long long)(b + 1) * gemmBlocks / T);
    if (hi > lo) {
        h8_t* Bl = (h8_t*)smem;
        const float4* s = (const float4*)W0swz;
        float4* d = (float4*)smem;
        for (int i = threadIdx.x; i < 1280; i += 512) d[i] = s[i];
        __syncthreads();
        gemm_body(lo, x, N, xw, as, ad, Bl);
    } else {
        int pb = b - hi;
        unsigned* stage = (unsigned*)smem;
        int* scnt = (int*)(smem + NBMAX * STRIDE * 4);
        int tid = threadIdx.x;
        for (int i = tid; i < NB; i += 512) scnt[i] = 0;
        __syncthreads();
        int e0 = pb * perBlock, e1 = min(E, e0 + perBlock);
        // single staging pass (~3 edges/thread), overflow goes direct
        for (int i = e0 + tid; i < e1; i += 512) {
            int d2 = dst[i], s2 = src[i];
            int bk = d2 >> 10;
            unsigned rec = ((unsigned)(d2 & 1023) << 22) | (unsigned)s2;
            int pos = atomicAdd(&scnt[bk], 1);
            if (pos < CAPS) {
                stage[bk * STRIDE + pos] = rec;
            } else {
                int g = atomicAdd(&gcur[bk], 1);
                bucketBuf[(size_t)bk * cap + g] = rec;
            }
        }
        __syncthreads();
        // one cooperative flush: thread tid owns bucket tid
        if (tid < NB) {
            int n = min(scnt[tid], CAPS);
            if (n > 0) {
                int gb2 = atomicAdd(&gcur[tid], n);
                unsigned* gp = &bucketBuf[(size_t)tid * cap + gb2];
                for (int j = 0; j < n; j++) gp[j] = stage[tid * STRIDE + j];
            }
        }
    }
}

// ---------------- phase2: per-bucket CSR build ----------------
__global__ __launch_bounds__(256) void kP2(
    const unsigned* __restrict__ bucketBuf, const int* __restrict__ gcur,
    int NB, int cap, int N, int* __restrict__ row, int* __restrict__ adj)
{
    __shared__ int deg[1024];
    __shared__ int curl[1024];
    __shared__ int sc[256];
    int b = blockIdx.x, tid = threadIdx.x;
    int lo = b << 10;
    int hi = min(N, lo + 1024);
    int cnt = hi - lo;
    int size = min(gcur[b], cap);
    sc[tid] = (tid < b) ? gcur[tid] : 0;
    __syncthreads();
    for (int off = 128; off > 0; off >>= 1) {
        if (tid < off) sc[tid] += sc[tid + off];
        __syncthreads();
    }
    int bbase = sc[0];
    __syncthreads();
    for (int i = tid; i < 1024; i += 256) deg[i] = 0;
    __syncthreads();
    const unsigned* buf = bucketBuf + (size_t)b * cap;
    for (int e = tid; e < size; e += 256) atomicAdd(&deg[buf[e] >> 22], 1);
    __syncthreads();
    int dv[4]; int s = 0;
    #pragma unroll
    for (int j = 0; j < 4; j++) { dv[j] = deg[tid * 4 + j]; s += dv[j]; }
    sc[tid] = s; __syncthreads();
    for (int off = 1; off < 256; off <<= 1) {
        int xv = (tid >= off) ? sc[tid - off] : 0;
        __syncthreads();
        sc[tid] += xv;
        __syncthreads();
    }
    int o = (tid ? sc[tid - 1] : 0);
    #pragma unroll
    for (int j = 0; j < 4; j++) {
        int loc = tid * 4 + j;
        curl[loc] = o;
        if (loc < cnt) row[lo + loc] = bbase + o;
        o += dv[j];
    }
    if (b == NB - 1 && tid == 0) row[N] = bbase + size;
    __syncthreads();
    for (int e = tid; e < size; e += 256) {
        unsigned r = buf[e];
        int l = r >> 22;
        int p = atomicAdd(&curl[l], 1);
        adj[bbase + p] = (int)(r & 0x3FFFFF);
    }
}

// ---------------- layer0 aggregation + fused layer1 transform (R11) ----------
__global__ __launch_bounds__(256) void k_agg8_tf1(
    const __half* __restrict__ xw, const float* __restrict__ as, const float* __restrict__ ad,
    const int* __restrict__ row, const int* __restrict__ adj,
    const float* __restrict__ bias, const float* __restrict__ W1,
    const float* __restrict__ aS1, const float* __restrict__ aD1,
    int N, __half* __restrict__ hw, float* __restrict__ as1, float* __restrict__ ad1)
{
    __shared__ h2_t Wl2[32 * 64];
    __shared__ h2_t hst[4 * 32];
    for (int i = threadIdx.x; i < 32 * 64; i += 256) {
        int k2 = i >> 6, c = i & 63;
        h2_t v;
        v.x = (_Float16)W1[(2 * k2) * 64 + c];
        v.y = (_Float16)W1[(2 * k2 + 1) * 64 + c];
        Wl2[i] = v;
    }
    __syncthreads();
    int wv = threadIdx.x >> 6;
    int n = (blockIdx.x * 256 + threadIdx.x) >> 6;
    int lane = threadIdx.x & 63;
    if (n >= N) return;
    int rs = row[n], re = row[n + 1];
    int hh = lane & 7;
    int e8 = lane >> 3;
    int c2 = lane & 31;
    int ep = lane >> 5;
    int hq = c2 >> 2;
    const __half2* xw2 = (const __half2*)xw;
    float adv = ad[(size_t)n * 8 + hh];
    float shift = lrelu(as[(size_t)n * 8 + hh] + adv);
    float2 acc;
    {
        float2 f = __half22float2(xw2[(size_t)n * 32 + c2]);
        acc.x = ep ? 0.f : f.x;
        acc.y = ep ? 0.f : f.y;
    }
    float dsum = 0.f;
    int j = rs;
    bool have = (j + 8 <= re);
    int   sC = have ? adj[j + e8] : 0;
    float eC = have ? lrelu(as[(size_t)sC * 8 + hh] + adv) : 0.f;
    while (have) {
        int jn = j + 8;
        bool haveN = (jn + 8 <= re);
        int sN = haveN ? adj[jn + e8] : 0;
        float w = __expf(eC - shift);
        dsum += w;
        float eN = haveN ? lrelu(as[(size_t)sN * 8 + hh] + adv) : 0.f;
        #pragma unroll
        for (int t = 0; t < 8; t += 2) {
            int   te = t + ep;
            float we = __shfl(w, te * 8 + hq, 64);
            int   se = __shfl(sC, te * 8, 64);
            float2 xv = __half22float2(xw2[(size_t)se * 32 + c2]);
            acc.x = fmaf(we, xv.x, acc.x);
            acc.y = fmaf(we, xv.y, acc.y);
        }
        sC = sN; eC = eN; j = jn; have = haveN;
    }
    int rem = re - j;
    if (rem > 0) {
        int jj = j + e8;
        bool v = jj < re;
        int st = adj[v ? jj : rs];
        float e = lrelu(as[(size_t)st * 8 + hh] + adv);
        float w = v ? __expf(e - shift) : 0.f;
        dsum += w;
        for (int t = 0; t < rem; t += 2) {
            int   te = t + ep;
            float we = __shfl(w, te * 8 + hq, 64);
            int   se = __shfl(st, te * 8, 64);
            float2 xv = __half22float2(xw2[(size_t)se * 32 + c2]);
            acc.x = fmaf(we, xv.x, acc.x);
            acc.y = fmaf(we, xv.y, acc.y);
        }
    }
    acc.x += __shfl_xor(acc.x, 32, 64);
    acc.y += __shfl_xor(acc.y, 32, 64);
    dsum += __shfl_xor(dsum, 8, 64);
    dsum += __shfl_xor(dsum, 16, 64);
    dsum += __shfl_xor(dsum, 32, 64);
    float denom = 1.f + __shfl(dsum, hq, 64);
    float2 bi = ((const float2*)bias)[c2];
    float hx = eluf(acc.x / denom + bi.x);
    float hy = eluf(acc.y / denom + bi.y);
    if (ep == 0) {
        h2_t hv;
        hv.x = (_Float16)hx;
        hv.y = (_Float16)hy;
        hst[wv * 32 + c2] = hv;
    }
    float a1 = 0.f;
    #pragma unroll
    for (int k2 = 0; k2 < 32; k2++) {
        h2_t hp = hst[wv * 32 + k2];
        h2_t wp = Wl2[k2 * 64 + lane];
        a1 = __builtin_amdgcn_fdot2(hp, wp, a1, false);
    }
    hw[(size_t)n * 64 + lane] = __float2half(a1);
    float ps = a1 * aS1[lane], pd = a1 * aD1[lane];
    #pragma unroll
    for (int off = 1; off < 64; off <<= 1) {
        ps += __shfl_xor(ps, off, 64);
        pd += __shfl_xor(pd, off, 64);
    }
    if (lane == 0) { as1[n] = ps; ad1[n] = pd; }
}

// ---------------- layer1 aggregation (R11) ----------------
__global__ __launch_bounds__(256) void k_agg1(
    const __half* __restrict__ hw, const float* __restrict__ as, const float* __restrict__ ad,
    const int* __restrict__ row, const int* __restrict__ adj,
    const float* __restrict__ bias, int N, float* __restrict__ outp)
{
    int n = (blockIdx.x * 256 + threadIdx.x) >> 6;
    int lane = threadIdx.x & 63;
    if (n >= N) return;
    int rs = row[n], re = row[n + 1];
    int e8 = lane >> 3;
    int c2 = lane & 31;
    int ep = lane >> 5;
    const __half2* hw2 = (const __half2*)hw;
    float adv = ad[n];
    float shift = lrelu(as[n] + adv);
    float2 acc;
    {
        float2 f = __half22float2(hw2[(size_t)n * 32 + c2]);
        acc.x = ep ? 0.f : f.x;
        acc.y = ep ? 0.f : f.y;
    }
    float dsum = 0.f;
    int j = rs;
    bool have = (j + 8 <= re);
    int   sC = have ? adj[j + e8] : 0;
    float eC = have ? lrelu(as[sC] + adv) : 0.f;
    while (have) {
        int jn = j + 8;
        bool haveN = (jn + 8 <= re);
        int sN = haveN ? adj[jn + e8] : 0;
        float w = __expf(eC - shift);
        dsum += w;
        float eN = haveN ? lrelu(as[sN] + adv) : 0.f;
        #pragma unroll
        for (int t = 0; t < 8; t += 2) {
            int   te = t + ep;
            float we = __shfl(w, te * 8, 64);
            int   se = __shfl(sC, te * 8, 64);
            float2 xv = __half22float2(hw2[(size_t)se * 32 + c2]);
            acc.x = fmaf(we, xv.x, acc.x);
            acc.y = fmaf(we, xv.y, acc.y);
        }
        sC = sN; eC = eN; j = jn; have = haveN;
    }
    int rem = re - j;
    if (rem > 0) {
        int jj = j + e8;
        bool v = jj < re;
        int st = adj[v ? jj : rs];
        float e = lrelu(as[st] + adv);
        float w = v ? __expf(e - shift) : 0.f;
        dsum += w;
        for (int t = 0; t < rem; t += 2) {
            int   te = t + ep;
            float we = __shfl(w, te * 8, 64);
            int   se = __shfl(st, te * 8, 64);
            float2 xv = __half22float2(hw2[(size_t)se * 32 + c2]);
            acc.x = fmaf(we, xv.x, acc.x);
            acc.y = fmaf(we, xv.y, acc.y);
        }
    }
    acc.x += __shfl_xor(acc.x, 32, 64);
    acc.y += __shfl_xor(acc.y, 32, 64);
    dsum += __shfl_xor(dsum, 8, 64);
    dsum += __shfl_xor(dsum, 16, 64);
    dsum += __shfl_xor(dsum, 32, 64);
    float denom = 1.f + dsum;
    if (ep == 0) {
        float2 bi = ((const float2*)bias)[c2];
        float2 o;
        o.x = eluf(acc.x / denom + bi.x);
        o.y = eluf(acc.y / denom + bi.y);
        ((float2*)outp)[(size_t)n * 32 + c2] = o;
    }
}

extern "C" void kernel_launch(void* const* d_in, const int* in_sizes, int n_in,
                              void* d_out, int out_size, void* d_ws, size_t ws_size,
                              hipStream_t stream)
{
    const float* x   = (const float*)d_in[0];
    const int*   ei  = (const int*)d_in[1];
    const float* W0  = (const float*)d_in[2];
    const float* aS0 = (const float*)d_in[3];
    const float* aD0 = (const float*)d_in[4];
    const float* b0  = (const float*)d_in[5];
    const float* W1  = (const float*)d_in[6];
    const float* aS1 = (const float*)d_in[7];
    const float* aD1 = (const float*)d_in[8];
    const float* b1  = (const float*)d_in[9];

    const int N = in_sizes[0] / 128;
    const int E = in_sizes[1] / 2;
    const int* srcp = ei;
    const int* dstp = ei + E;

    const int NB  = (N + 1023) >> 10;
    const int cap = E / NB + 4096;

    char* ws = (char*)d_ws;
    size_t off = 0;
    auto alloc = [&](size_t bytes) -> size_t {
        size_t o = off;
        off = (o + bytes + 255) & ~(size_t)255;
        return o;
    };
    __half* B1 = (__half*)(ws + alloc((size_t)N * 64 * 2));     // xw (half)
    size_t b2Bytes = (size_t)N * 64 * 2;
    size_t bkBytes = (size_t)NB * cap * 4;
    char*  region  = ws + alloc(b2Bytes > bkBytes ? b2Bytes : bkBytes);
    __half*   B2        = (__half*)region;     // hw overlays bucketBuf
    unsigned* bucketBuf = (unsigned*)region;
    float* as0 = (float*)(ws + alloc((size_t)N * 8 * 4));
    float* ad0 = (float*)(ws + alloc((size_t)N * 8 * 4));
    float* as1 = (float*)(ws + alloc((size_t)N * 4));
    float* ad1 = (float*)(ws + alloc((size_t)N * 4));
    int*   row = (int*)(ws + alloc((size_t)(N + 1) * 4));
    int*   adj = (int*)(ws + alloc((size_t)E * 4));
    int*  gcur = (int*)(ws + alloc((size_t)NB * 4));
    __half* W0swz = (__half*)(ws + alloc(1280 * 8 * 2));

    const int gemmBlocks = (N + 127) / 128;
    const int binBlocks  = 1024;
    const int perBlock   = (E + binBlocks - 1) / binBlocks;

    hipMemsetAsync(gcur, 0, (size_t)NB * 4, stream);
    kPrep<<<1, 256, 0, stream>>>(W0, aS0, aD0, W0swz);
    kGB<<<gemmBlocks + binBlocks, 512, 0, stream>>>(
        x, W0swz, N, B1, as0, ad0, gemmBlocks,
        srcp, dstp, E, perBlock, bucketBuf, gcur, NB, cap, binBlocks);
    kP2<<<NB, 256, 0, stream>>>(bucketBuf, gcur, NB, cap, N, row, adj);

    const int agBlocks = (N + 3) / 4;
    k_agg8_tf1<<<agBlocks, 256, 0, stream>>>(B1, as0, ad0, row, adj, b0,
                                             W1, aS1, aD1, N, B2, as1, ad1);
    k_agg1<<<agBlocks, 256, 0, stream>>>(B2, as1, ad1, row, adj, b1, N, (float*)d_out);
}